// Round 2
// baseline (1217.194 us; speedup 1.0000x reference)
//
#include <hip/hip_runtime.h>
#include <hip/hip_bf16.h>

#define CH   96
#define KOFF 27
#define TM   64          // rows per block
#define LDG  104         // padded LDS row stride (elements): 208B -> 2-way bank alias max

typedef __bf16 bf16x8 __attribute__((ext_vector_type(8)));
typedef float  floatx4 __attribute__((ext_vector_type(4)));

static __device__ inline uint pk_bf16(float a, float b) {
    __hip_bfloat162 h = __float22bfloat162_rn(make_float2(a, b));
    return *(uint*)&h;
}

// W[k][j][c] fp32 (j = in-ch, c = out-ch)  ->  Wt[k][c][j] bf16
__global__ __launch_bounds__(256) void transpose_w(
    const float* __restrict__ W1, const float* __restrict__ W2,
    ushort* __restrict__ Wt1, ushort* __restrict__ Wt2)
{
    int k = blockIdx.x;                 // 0..53
    const float* src = (k < KOFF) ? (W1 + (size_t)k * CH * CH)
                                  : (W2 + (size_t)(k - KOFF) * CH * CH);
    ushort*      dst = (k < KOFF) ? (Wt1 + (size_t)k * CH * CH)
                                  : (Wt2 + (size_t)(k - KOFF) * CH * CH);
    for (int i = threadIdx.x; i < CH * CH; i += blockDim.x) {
        int j = i / CH;
        int c = i - j * CH;
        __hip_bfloat16 h = __float2bfloat16(src[i]);
        dst[c * CH + j] = *(ushort*)&h;
    }
}

// PASS 0: fin = fp32 feats, out = bf16 x, no residual
// PASS 1: fin = bf16 x,     out = fp32,  residual = fp32 feats
template<int PASS>
__global__ __launch_bounds__(256) void sconv(
    const void*  __restrict__ fin_,
    const int*   __restrict__ nidx,          // [27][N]
    const int*   __restrict__ nmask,         // [27][N]
    const ushort* __restrict__ Wt,           // [27][96][96] bf16, Wt[k][c][j]
    const float* __restrict__ bias,          // [96] fp32
    const float* __restrict__ alpha,         // [1] fp32
    const float* __restrict__ resid,         // [N][96] fp32 or nullptr
    void*        __restrict__ fout_,
    int N)
{
    __shared__ ushort G[TM * LDG];    // gathered rows (bf16), 13.3 KB
    __shared__ ushort Ws[CH * LDG];   // transposed weight tile (bf16), 20 KB

    const int tid  = threadIdx.x;
    const int lane = tid & 63;
    const int wid  = tid >> 6;        // 0..3
    const int quad = lane >> 4;       // 0..3
    const int col0 = lane & 15;
    const int base = blockIdx.x * TM;

    floatx4 acc[6];
#pragma unroll
    for (int i = 0; i < 6; ++i) acc[i] = (floatx4){0.f, 0.f, 0.f, 0.f};

    const int r = tid >> 2;           // staging row 0..63
    const int q = tid & 3;            // staging quarter of a row

    for (int k = 0; k < KOFF; ++k) {
        __syncthreads();              // previous iter's LDS reads done
        // --- stage gathered, mask-zeroed feature rows (convert to bf16 if fp32) ---
        {
            int n   = base + r;
            int idx = nidx[(size_t)k * N + n];
            int msk = nmask[(size_t)k * N + n];
            if (PASS == 0) {
                const float4* src = (const float4*)((const float*)fin_ + (size_t)idx * CH);
                float4 f[6];
                float4 z; z.x = z.y = z.z = z.w = 0.f;
#pragma unroll
                for (int i = 0; i < 6; ++i) f[i] = msk ? src[q * 6 + i] : z;
                uint p[12];
#pragma unroll
                for (int i = 0; i < 6; ++i) {
                    p[2 * i]     = pk_bf16(f[i].x, f[i].y);
                    p[2 * i + 1] = pk_bf16(f[i].z, f[i].w);
                }
                uint4* dst = (uint4*)(G + r * LDG + q * 24);
#pragma unroll
                for (int i = 0; i < 3; ++i) {
                    uint4 v; v.x = p[4*i]; v.y = p[4*i+1]; v.z = p[4*i+2]; v.w = p[4*i+3];
                    dst[i] = v;
                }
            } else {
                const uint4* src = (const uint4*)((const ushort*)fin_ + (size_t)idx * CH);
                uint4* dst = (uint4*)(G + r * LDG);
                uint4 z; z.x = z.y = z.z = z.w = 0u;
#pragma unroll
                for (int i = 0; i < 3; ++i) {
                    uint4 v = msk ? src[q + 4 * i] : z;
                    dst[q + 4 * i] = v;
                }
            }
        }
        // --- stage Wt[k] (bf16) into padded LDS ---
        {
            const uint4* src = (const uint4*)(Wt + (size_t)k * CH * CH);
            for (int i = tid; i < CH * (CH / 8); i += 256) {
                int row = i / (CH / 8);
                int off = i - row * (CH / 8);
                *((uint4*)(Ws + row * LDG) + off) = src[i];
            }
        }
        __syncthreads();
        // --- MFMA 16x16x32 bf16: wave owns rows [wid*16, wid*16+16) ---
        const int mrow = wid * 16 + col0;
#pragma unroll
        for (int kk = 0; kk < 3; ++kk) {
            bf16x8 a = *(const bf16x8*)(G + mrow * LDG + kk * 32 + quad * 8);
#pragma unroll
            for (int nt = 0; nt < 6; ++nt) {
                bf16x8 b = *(const bf16x8*)(Ws + (nt * 16 + col0) * LDG + kk * 32 + quad * 8);
                acc[nt] = __builtin_amdgcn_mfma_f32_16x16x32_bf16(a, b, acc[nt], 0, 0, 0);
            }
        }
    }

    // --- epilogue: bias, optional residual, PReLU ---
    float al = alpha[0];
#pragma unroll
    for (int nt = 0; nt < 6; ++nt) {
        int c = nt * 16 + col0;
        float bv = bias[c];
#pragma unroll
        for (int rr = 0; rr < 4; ++rr) {
            int row = base + wid * 16 + quad * 4 + rr;
            float v = acc[nt][rr] + bv;
            if (PASS == 1) v += resid[(size_t)row * CH + c];
            v = (v > 0.f) ? v : al * v;
            if (PASS == 0) {
                __hip_bfloat16 h = __float2bfloat16(v);
                ((ushort*)fout_)[(size_t)row * CH + c] = *(ushort*)&h;
            } else {
                ((float*)fout_)[(size_t)row * CH + c] = v;
            }
        }
    }
}

extern "C" void kernel_launch(void* const* d_in, const int* in_sizes, int n_in,
                              void* d_out, int out_size, void* d_ws, size_t ws_size,
                              hipStream_t stream)
{
    const float* feats = (const float*)d_in[0];
    const int*   nidx  = (const int*)d_in[1];
    const int*   nmask = (const int*)d_in[2];
    const float* W1    = (const float*)d_in[3];
    const float* b1    = (const float*)d_in[4];
    const float* a1    = (const float*)d_in[5];
    const float* W2    = (const float*)d_in[6];
    const float* b2    = (const float*)d_in[7];
    const float* a2    = (const float*)d_in[8];

    const int N = in_sizes[0] / CH;   // 262144

    // workspace layout: Wt1 | Wt2 | x (bf16)   -> ~51.3 MB total
    ushort* Wt1 = (ushort*)d_ws;
    ushort* Wt2 = Wt1 + (size_t)KOFF * CH * CH;
    ushort* x   = Wt2 + (size_t)KOFF * CH * CH;

    transpose_w<<<2 * KOFF, 256, 0, stream>>>(W1, W2, Wt1, Wt2);

    // conv1: x = bf16( PReLU(sum_k gather_f32(feats) @ W1[k] + b1, a1) )
    sconv<0><<<N / TM, 256, 0, stream>>>(
        (const void*)feats, nidx, nmask, Wt1, b1, a1, nullptr, (void*)x, N);

    // conv2: out = PReLU(sum_k gather_bf16(x) @ W2[k] + b2 + feats, a2)  (fp32 out)
    sconv<1><<<N / TM, 256, 0, stream>>>(
        (const void*)x, nidx, nmask, Wt2, b2, a2, feats, d_out, N);
}

// Round 3
// 858.315 us; speedup vs baseline: 1.4181x; 1.4181x over previous
//
#include <hip/hip_runtime.h>
#include <hip/hip_bf16.h>

#define CH     96
#define KOFF   27
#define TM     128            // rows per block = 4 waves x 32 rows
#define NCHUNK 1280           // 16B chunks per k weight tile (1152 used + pad to 5*256)

typedef __bf16 bf16x8 __attribute__((ext_vector_type(8)));
typedef float  floatx4 __attribute__((ext_vector_type(4)));

typedef const __attribute__((address_space(1))) unsigned int* as1_u32p;
typedef __attribute__((address_space(3))) unsigned int*       as3_u32p;

static __device__ inline uint pk_bf16(float a, float b) {
    __hip_bfloat162 h = __float22bfloat162_rn(make_float2(a, b));
    return *(uint*)&h;
}

// W[k][j][c] fp32 -> bf16 MFMA B-fragment image:
// chunk c in [0,1152): f=c>>6 (f = nt*3+kk), lane=c&63;
// chunk = 8 bf16: W[k][kk*32+(lane>>4)*8 + j][nt*16+(lane&15)], j=0..7
__global__ __launch_bounds__(256) void make_frags(
    const float* __restrict__ W1, const float* __restrict__ W2,
    uint4* __restrict__ Wf1, uint4* __restrict__ Wf2)
{
    int k = blockIdx.x;               // 0..53
    const float* src = (k < KOFF) ? (W1 + (size_t)k * CH * CH)
                                  : (W2 + (size_t)(k - KOFF) * CH * CH);
    uint4* dst = ((k < KOFF) ? Wf1 : Wf2) + (size_t)(k % KOFF) * NCHUNK;
    for (int c = threadIdx.x; c < 1152; c += 256) {
        int f    = c >> 6;
        int lane = c & 63;
        int nt = f / 3, kk = f - nt * 3;
        int jb  = kk * 32 + (lane >> 4) * 8;
        int col = nt * 16 + (lane & 15);
        uint p[4];
#pragma unroll
        for (int h = 0; h < 4; ++h)
            p[h] = pk_bf16(src[(size_t)(jb + 2 * h) * CH + col],
                           src[(size_t)(jb + 2 * h + 1) * CH + col]);
        uint4 v; v.x = p[0]; v.y = p[1]; v.z = p[2]; v.w = p[3];
        dst[c] = v;
    }
}

// PASS 0: fin = fp32 feats -> out bf16 x (no residual)
// PASS 1: fin = bf16 x     -> out fp32, residual = fp32 feats
template<int PASS>
__global__ __launch_bounds__(256, 3) void sconv(
    const void* __restrict__ fin_,
    const int*  __restrict__ nidx,        // [27][N]
    const int*  __restrict__ nmask,       // [27][N]
    const uint4* __restrict__ Wf,         // [27][NCHUNK] fragment image
    const float* __restrict__ bias,
    const float* __restrict__ alpha,
    const float* __restrict__ resid,
    void* __restrict__ fout_,
    int N)
{
    __shared__ uint4 WsL[2 * NCHUNK];     // 40 KB, double-buffered weight tile

    const int tid   = threadIdx.x;
    const int lane  = tid & 63;
    const int wid   = tid >> 6;
    const int quad  = lane >> 4;
    const int col0  = lane & 15;
    const int wbase = blockIdx.x * TM + wid * 32;   // this wave's 32 rows
    const int myrow = wbase + (lane & 31);

    // bit-pack all 27 neighbor masks for my row into one VGPR
    uint mbits = 0;
    for (int k = 0; k < KOFF; ++k)
        mbits |= (nmask[(size_t)k * N + myrow] != 0 ? 1u : 0u) << k;
    const uint mb0 = (uint)__shfl((int)mbits, col0, 64);        // rows wbase+col0
    const uint mb1 = (uint)__shfl((int)mbits, 16 + col0, 64);   // rows wbase+16+col0

    // kick weight stage for k=0 into buffer 0 (wave-uniform LDS base + lane*16)
    {
        const uint4* g = Wf;
#pragma unroll
        for (int r = 0; r < 5; ++r) {
            int cbase = r * 256 + wid * 64;
            __builtin_amdgcn_global_load_lds(
                (as1_u32p)(const void*)(g + cbase + lane),
                (as3_u32p)(void*)(&WsL[cbase]), 16, 0, 0);
        }
    }

    int idxv = nidx[myrow];   // neighbor index, k = 0

    floatx4 acc[2][6];
#pragma unroll
    for (int mt = 0; mt < 2; ++mt)
#pragma unroll
        for (int nt = 0; nt < 6; ++nt)
            acc[mt][nt] = (floatx4){0.f, 0.f, 0.f, 0.f};

    for (int k = 0; k < KOFF; ++k) {
        const int buf = k & 1;
        const int i0  = __shfl(idxv, col0, 64);
        const int i1  = __shfl(idxv, 16 + col0, 64);
        const uint s0 = (uint)-(int)((mb0 >> k) & 1u);
        const uint s1 = (uint)-(int)((mb1 >> k) & 1u);

        __syncthreads();   // Ws[buf] staged (vmcnt drained); readers of Ws[buf^1] done

        if (k + 1 < KOFF) {
            const uint4* g = Wf + (size_t)(k + 1) * NCHUNK;
#pragma unroll
            for (int r = 0; r < 5; ++r) {
                int cbase = r * 256 + wid * 64;
                __builtin_amdgcn_global_load_lds(
                    (as1_u32p)(const void*)(g + cbase + lane),
                    (as3_u32p)(void*)(&WsL[(buf ^ 1) * NCHUNK + cbase]), 16, 0, 0);
            }
            idxv = nidx[(size_t)(k + 1) * N + myrow];
        }

#pragma unroll
        for (int kk = 0; kk < 3; ++kk) {
            uint4 r0, r1;
            if (PASS == 1) {
                const uint4* xs = (const uint4*)fin_;       // bf16 rows, 12 chunks/row
                r0 = xs[(size_t)i0 * 12 + kk * 4 + quad];
                r1 = xs[(size_t)i1 * 12 + kk * 4 + quad];
            } else {
                const float4* fs = (const float4*)fin_;     // fp32 rows, 24 float4/row
                float4 lo0 = fs[(size_t)i0 * 24 + kk * 8 + quad * 2];
                float4 hi0 = fs[(size_t)i0 * 24 + kk * 8 + quad * 2 + 1];
                float4 lo1 = fs[(size_t)i1 * 24 + kk * 8 + quad * 2];
                float4 hi1 = fs[(size_t)i1 * 24 + kk * 8 + quad * 2 + 1];
                r0.x = pk_bf16(lo0.x, lo0.y); r0.y = pk_bf16(lo0.z, lo0.w);
                r0.z = pk_bf16(hi0.x, hi0.y); r0.w = pk_bf16(hi0.z, hi0.w);
                r1.x = pk_bf16(lo1.x, lo1.y); r1.y = pk_bf16(lo1.z, lo1.w);
                r1.z = pk_bf16(hi1.x, hi1.y); r1.w = pk_bf16(hi1.z, hi1.w);
            }
            r0.x &= s0; r0.y &= s0; r0.z &= s0; r0.w &= s0;
            r1.x &= s1; r1.y &= s1; r1.z &= s1; r1.w &= s1;
            bf16x8 a0 = *(bf16x8*)&r0;
            bf16x8 a1 = *(bf16x8*)&r1;
#pragma unroll
            for (int nt = 0; nt < 6; ++nt) {
                bf16x8 b = *(bf16x8*)&WsL[buf * NCHUNK + (nt * 3 + kk) * 64 + lane];
                acc[0][nt] = __builtin_amdgcn_mfma_f32_16x16x32_bf16(a0, b, acc[0][nt], 0, 0, 0);
                acc[1][nt] = __builtin_amdgcn_mfma_f32_16x16x32_bf16(a1, b, acc[1][nt], 0, 0, 0);
            }
        }
    }

    const float al = alpha[0];
#pragma unroll
    for (int mt = 0; mt < 2; ++mt) {
#pragma unroll
        for (int nt = 0; nt < 6; ++nt) {
            const int c  = nt * 16 + col0;
            const float bv = bias[c];
#pragma unroll
            for (int rr = 0; rr < 4; ++rr) {
                const int row = wbase + mt * 16 + quad * 4 + rr;
                float v = acc[mt][nt][rr] + bv;
                if (PASS == 1) v += resid[(size_t)row * CH + c];
                v = (v > 0.f) ? v : al * v;
                if (PASS == 0) {
                    __hip_bfloat16 h = __float2bfloat16(v);
                    ((ushort*)fout_)[(size_t)row * CH + c] = *(ushort*)&h;
                } else {
                    ((float*)fout_)[(size_t)row * CH + c] = v;
                }
            }
        }
    }
}

extern "C" void kernel_launch(void* const* d_in, const int* in_sizes, int n_in,
                              void* d_out, int out_size, void* d_ws, size_t ws_size,
                              hipStream_t stream)
{
    const float* feats = (const float*)d_in[0];
    const int*   nidx  = (const int*)d_in[1];
    const int*   nmask = (const int*)d_in[2];
    const float* W1    = (const float*)d_in[3];
    const float* b1    = (const float*)d_in[4];
    const float* a1    = (const float*)d_in[5];
    const float* W2    = (const float*)d_in[6];
    const float* b2    = (const float*)d_in[7];
    const float* a2    = (const float*)d_in[8];

    const int N = in_sizes[0] / CH;   // 262144

    // workspace: Wf1 | Wf2 (fragment images, 553 KB each) | x (bf16, 50.3 MB)
    uint4* Wf1 = (uint4*)d_ws;
    uint4* Wf2 = Wf1 + (size_t)KOFF * NCHUNK;
    ushort* x  = (ushort*)(Wf2 + (size_t)KOFF * NCHUNK);

    make_frags<<<2 * KOFF, 256, 0, stream>>>(W1, W2, Wf1, Wf2);

    sconv<0><<<N / TM, 256, 0, stream>>>(
        (const void*)feats, nidx, nmask, Wf1, b1, a1, nullptr, (void*)x, N);

    sconv<1><<<N / TM, 256, 0, stream>>>(
        (const void*)x, nidx, nmask, Wf2, b2, a2, feats, d_out, N);
}